// Round 8
// baseline (350.672 us; speedup 1.0000x reference)
//
#include <hip/hip_runtime.h>
#include <hip/hip_bf16.h>

// B=2, S=1024, L=1024, DIM_Q=2048, H=16, K=128, D_C=512, D_CQ=1536, R=64

typedef __attribute__((ext_vector_type(8))) short short8;
typedef __attribute__((ext_vector_type(4))) float f32x4;

__device__ __forceinline__ unsigned short f2bs(float v){
  __hip_bfloat16 b = __float2bfloat16(v);
  return *reinterpret_cast<unsigned short*>(&b);
}
__device__ __forceinline__ void storeC(float* p, float v){ *p = v; }
__device__ __forceinline__ void storeC(unsigned short* p, float v){ *p = f2bs(v); }

// async global->LDS, 16B per lane.  LDS dest = wave-uniform base + lane*16.
__device__ __forceinline__ void gl_lds16(const void* g, void* l){
  __builtin_amdgcn_global_load_lds(
      (const __attribute__((address_space(1))) unsigned int*)g,
      (__attribute__((address_space(3))) unsigned int*)l, 16, 0, 0);
}

// counted vmcnt wait (immediate must be a literal in the asm string)
template<int N> __device__ __forceinline__ void wait_vmcnt(){
  if constexpr (N==0)       asm volatile("s_waitcnt vmcnt(0)" ::: "memory");
  else if constexpr (N==3)  asm volatile("s_waitcnt vmcnt(3)" ::: "memory");
  else if constexpr (N==4)  asm volatile("s_waitcnt vmcnt(4)" ::: "memory");
  else if constexpr (N==6)  asm volatile("s_waitcnt vmcnt(6)" ::: "memory");
  else if constexpr (N==8)  asm volatile("s_waitcnt vmcnt(8)" ::: "memory");
  else if constexpr (N==14) asm volatile("s_waitcnt vmcnt(14)" ::: "memory");
  else if constexpr (N==16) asm volatile("s_waitcnt vmcnt(16)" ::: "memory");
  else if constexpr (N==22) asm volatile("s_waitcnt vmcnt(22)" ::: "memory");
  else static_assert(N==0, "unsupported vmcnt");
}

// ---------------------------------------------------------------------------
// transpose helper: fp32 [R,Cn] tile -> bf16 [Cn,R], one 32x32 tile per block
__device__ __forceinline__ void transpose_tile(
    const float* ip, unsigned short* op, int R, int Cn, int c0, int r0)
{
  __shared__ float tile[32][33];
  int tr = threadIdx.x>>5, tc = threadIdx.x&31;
  #pragma unroll
  for (int i=0;i<4;i++)
    tile[tr+i*8][tc] = ip[(long)(r0+tr+i*8)*Cn + c0+tc];
  __syncthreads();
  #pragma unroll
  for (int i=0;i<4;i++)
    op[(long)(c0+tr+i*8)*R + r0+tc] = f2bs(tile[tc][tr+i*8]);
}

// ---------------------------------------------------------------------------
// prep_all: packed q-RoPE table, fused k-RoPE (kv_c -> kv_rb bf16, no tables),
// 4 fp32->bf16 converts, and the 3 weight transposes — one launch.
__global__ __launch_bounds__(256) void prep_all(
    float4* __restrict__ rq,
    const float* __restrict__ kvc, unsigned short* __restrict__ kvrb,
    const float* __restrict__ hidden, unsigned short* __restrict__ hiddenb,
    const float* __restrict__ Wq, unsigned short* __restrict__ Wqb,
    const float* __restrict__ wkckv, unsigned short* __restrict__ wkckvb,
    const float* __restrict__ Wo, unsigned short* __restrict__ Wob,
    const float* __restrict__ wkcq, unsigned short* __restrict__ wkcqT,
    const float* __restrict__ Wqr, unsigned short* __restrict__ WqrT,
    const float* __restrict__ Wkr, unsigned short* __restrict__ WkrT)
{
  int blk = blockIdx.x;
  if (blk < 3072){
    int idx = blk*256 + threadIdx.x;          // < 1024*768
    int s = idx / 768, j = idx - (idx/768)*768;
    int i1 = j >> 1;                          // freq index (repeat_interleave(2))
    const float cst = -0.011992631f;          // -2*ln(10000)/1536
    float f1 = (float)s * __expf(cst * (float)i1);
    float f2 = (float)s * __expf(cst * (float)(384 + i1));
    float s1, c1, s2, c2;
    __sincosf(f1, &s1, &c1);
    __sincosf(f2, &s2, &c2);
    rq[idx] = make_float4(c1, s1, c2, s2);
    return;
  }
  if (blk < 4096){
    // fused k-RoPE: 2*1024*128 threads, 4 outputs each (pairs d,d+1,d+256,d+257)
    int idx = (blk-3072)*256 + threadIdx.x;   // < 262144
    int i1 = idx & 127;
    int l  = (idx >> 7) & 1023;
    int bb = idx >> 17;
    const float cst = -0.035977892f;          // -ln(10000)/256
    float f1 = (float)l * __expf(cst * (float)i1);
    float f2 = (float)l * __expf(cst * (float)(128 + i1));
    float s1,c1,s2,c2; __sincosf(f1,&s1,&c1); __sincosf(f2,&s2,&c2);
    long base = ((long)bb*1024 + l)*512;
    float2 xlo = *(const float2*)&kvc[base + 2*i1];
    float2 xhi = *(const float2*)&kvc[base + 2*i1 + 256];
    unsigned int lo = (unsigned)f2bs(xlo.x*c1 - xhi.x*s1)
                    | ((unsigned)f2bs(xlo.y*c1 - xhi.y*s1) << 16);
    unsigned int hi = (unsigned)f2bs(xhi.x*c2 + xlo.x*s2)
                    | ((unsigned)f2bs(xhi.y*c2 + xlo.y*s2) << 16);
    *(unsigned int*)&kvrb[base + 2*i1]       = lo;
    *(unsigned int*)&kvrb[base + 2*i1 + 256] = hi;
    return;
  }
  if (blk < 17408){
    const float* in; unsigned short* out; int i;
    if (blk < 8192){ in = hidden; out = hiddenb; i = (blk-4096)*256 + threadIdx.x; }
    else if (blk < 12288){ in = Wq; out = Wqb; i = (blk-8192)*256 + threadIdx.x; }
    else if (blk < 13312){ in = wkckv; out = wkckvb; i = (blk-12288)*256 + threadIdx.x; }
    else { in = Wo; out = Wob; i = (blk-13312)*256 + threadIdx.x; }
    float4 v = *(const float4*)(in + (long)i*4);
    ushort4 u; u.x=f2bs(v.x); u.y=f2bs(v.y); u.z=f2bs(v.z); u.w=f2bs(v.w);
    *(ushort4*)(out + (long)i*4) = u;
    return;
  }
  if (blk < 20480){            // transpose w_kc_q [16][128,1536] -> [16][1536,128]
    int b2 = blk - 17408;
    int x = b2 % 48, rem = b2 / 48, y = rem % 4, z = rem >> 2;
    transpose_tile(wkcq + (long)z*196608, wkcqT + (long)z*196608,
                   128, 1536, x*32, y*32);
    return;
  }
  if (blk < 22016){            // transpose W_qr [16][1536,64] -> [16][64,1536]
    int b2 = blk - 20480;
    int x = b2 & 1, rem = b2 >> 1, y = rem % 48, z = rem / 48;
    transpose_tile(Wqr + (long)z*98304, WqrT + (long)z*98304,
                   1536, 64, x*32, y*32);
    return;
  }
  {                            // transpose W_kr [16][512,64] -> [16][64,512]
    int b2 = blk - 22016;
    int x = b2 & 1, y = (b2 >> 1) & 15, z = b2 >> 5;
    transpose_tile(Wkr + (long)z*32768, WkrT + (long)z*32768,
                   512, 64, x*32, y*32);
  }
}

// ---------------------------------------------------------------------------
// bf16 MFMA GEMM (NT), 4-buffer LDS pipeline with counted vmcnt.
template<int BM,int BN,int WM,int WN,typename TC>
__global__ __launch_bounds__(256) void gemm_mfma(
    const unsigned short* __restrict__ A, const unsigned short* __restrict__ B,
    TC* __restrict__ C,
    int Kd, int lda, int ldb, int ldc, int Hb,
    long sAb, long sAh, long sBb, long sBh, long sCb, long sCh)
{
  constexpr int MF = WM/16, NF = WN/16;
  constexpr int WGM = BM/WM;
  constexpr int AOPS = (4*BM)/256;
  constexpr int BOPS = (4*BN)/256;
  constexpr int STG  = AOPS + BOPS;   // gl_lds16 per thread per stage

  const int z = blockIdx.z, bb = z/Hb, hh = z - bb*Hb;
  const unsigned short* Ap = A + bb*sAb + hh*sAh;
  const unsigned short* Bp = B + bb*sBb + hh*sBh;
  TC* Cp = C + bb*sCb + hh*sCh;
  const int m0 = blockIdx.x*BM, n0 = blockIdx.y*BN;
  const int t = threadIdx.x, w = t>>6, l = t&63;
  const int wm0 = (w % WGM)*WM, wn0 = (w / WGM)*WN;
  const int lq = l>>4, lm = l&15;

  __shared__ __align__(16) unsigned short As[4][4*BM*8];
  __shared__ __align__(16) unsigned short Bs[4][4*BN*8];

  f32x4 acc[MF][NF];
  #pragma unroll
  for (int mf=0; mf<MF; ++mf)
    #pragma unroll
    for (int nf=0; nf<NF; ++nf)
      acc[mf][nf] = f32x4{0.f,0.f,0.f,0.f};

  auto stage = [&](int buf, int k0){
    #pragma unroll
    for (int o = 0; o < AOPS; ++o){
      int g = o*256 + t;
      int row = g & (BM-1), kq = g / BM;
      gl_lds16(Ap + (long)(m0+row)*lda + k0 + kq*8, &As[buf][(o*256 + w*64)*8]);
    }
    #pragma unroll
    for (int o = 0; o < BOPS; ++o){
      int g = o*256 + t;
      int row = g & (BN-1), kq = g / BN;
      gl_lds16(Bp + (long)(n0+row)*ldb + k0 + kq*8, &Bs[buf][(o*256 + w*64)*8]);
    }
  };

  const int nIter = Kd >> 5;
  stage(0, 0);
  if (1 < nIter) stage(1, 32);
  if (2 < nIter) stage(2, 64);

  for (int it = 0; it < nIter; ++it){
    const int cur = it & 3;
    const int rem = nIter - it;
    if (rem >= 3)      wait_vmcnt<2*STG>();
    else if (rem == 2) wait_vmcnt<STG>();
    else               wait_vmcnt<0>();
    __builtin_amdgcn_s_barrier();

    short8 af[MF], bfr[NF];
    #pragma unroll
    for (int mf=0; mf<MF; ++mf)
      af[mf] = *(const short8*)&As[cur][(lq*BM + wm0 + mf*16 + lm)*8];
    #pragma unroll
    for (int nf=0; nf<NF; ++nf)
      bfr[nf] = *(const short8*)&Bs[cur][(lq*BN + wn0 + nf*16 + lm)*8];
    #pragma unroll
    for (int mf=0; mf<MF; ++mf)
      #pragma unroll
      for (int nf=0; nf<NF; ++nf)
        acc[mf][nf] = __builtin_amdgcn_mfma_f32_16x16x32_bf16(
            af[mf], bfr[nf], acc[mf][nf], 0, 0, 0);

    if (it+3 < nIter) stage((it+3) & 3, (it+3)*32);
  }

  #pragma unroll
  for (int mf=0; mf<MF; ++mf){
    #pragma unroll
    for (int nf=0; nf<NF; ++nf){
      int row = m0 + wm0 + mf*16 + lq*4;
      int col = n0 + wn0 + nf*16 + lm;
      #pragma unroll
      for (int r=0; r<4; ++r)
        storeC(&Cp[(long)(row+r)*ldc + col], acc[mf][nf][r]);
    }
  }
}

// ---------------------------------------------------------------------------
// q_fused v5b: BM=64, 512 blocks (2/CU).  ONE barrier per chunk.
//  - W1 fragments: global -> registers, prefetched one chunk ahead (w1a/w1b
//    ping-pong via unroll-by-2).  NOTE: hi base is 768 (local idx 0..31),
//    unlike the LDS path's 736 (local idx 32..63) — r7's bug.
//  - PV k-split: each wave covers its OWN 32 P-cols (16 lo + 16 hi) for ALL
//    64 output cols with K=32 MFMAs -> P transpose is wave-private LDS
//    (lgkmcnt only, no barrier).  Cross-wave f32 reduction once at the end.
//  - Only W2 staged in LDS (2 gl_lds/chunk, dbuf).  Per-chunk: wait
//    vmcnt(16) (8 rq + 8 w1-prefetch newer) + barrier; stage issued
//    post-barrier (closes the overwrite hazard with a single barrier).
__global__ __launch_bounds__(256) void q_fused(
    const unsigned short* __restrict__ A,    // q_hk [2048][2048]
    const unsigned short* __restrict__ W1t,  // wkcqT [16][1536][128]
    const unsigned short* __restrict__ W2t,  // WqrT  [16][64][1536]
    const float4* __restrict__ rq,           // [1024][768]
    unsigned short* __restrict__ qrOut)      // q_rb [B,H,1024,64]
{
  const int z = blockIdx.z, bb = z>>4, hh = z&15;
  const int m0 = blockIdx.x*64;
  const unsigned short* Ap = A + (long)bb*2097152 + hh*128;   // row stride 2048
  const unsigned short* W1 = W1t + (long)hh*196608;           // [1536][128]
  const unsigned short* W2 = W2t + (long)hh*98304;            // [64][1536]
  unsigned short* qo = qrOut + ((long)z*1024 + m0)*64;

  const int t = threadIdx.x, w = t>>6, l = t&63;
  const int lq = l>>4, lm = l&15;
  const int wr = (w>>1)*32;      // wave row-block
  const int wc = w&1;            // wave col-half

  __shared__ __align__(16) unsigned short W2s[2][8*64*8];   // 16 KB
  __shared__ __align__(16) unsigned short Pp[4][32*36];     // 9 KB (wave-private)
  __shared__ float Fred[2][32][64];                         // 16 KB (end reduce)

  // A fragments once from global (L2/L3-resident): af[mf][ks]
  short8 af[2][4];
  #pragma unroll
  for (int mf=0; mf<2; ++mf)
    #pragma unroll
    for (int ks=0; ks<4; ++ks)
      af[mf][ks] = *(const short8*)&Ap[(long)(m0 + wr + mf*16 + lm)*2048 + (ks*4+lq)*8];

  // W1 fragment loads -> registers.  lo col = cn*32+wc*16+lm,
  // hi col = 768 + cn*32 + wc*16 + lm  (local index 0..31 => base 768!)
  auto loadW1 = [&](short8 (&dst)[8], int cn){
    #pragma unroll
    for (int ks=0; ks<4; ++ks){
      dst[ks*2]   = *(const short8*)&W1[(long)(cn*32 + wc*16 + lm)*128 + (ks*4+lq)*8];
      dst[ks*2+1] = *(const short8*)&W1[(long)(768 + cn*32 + wc*16 + lm)*128 + (ks*4+lq)*8];
    }
  };
  auto stageW2 = [&](int buf, int cn){
    #pragma unroll
    for (int o=0;o<2;++o){
      int g=o*256+t; int n=g&63, kq=g>>6;
      int qk = (kq<4) ? (cn*32+kq*8) : (736+cn*32+kq*8);   // kq>=4: 768+(kq-4)*8
      gl_lds16(W2 + (long)n*1536 + qk, &W2s[buf][(o*256+w*64)*8]);
    }
  };

  short8 w1a[8], w1b[8];
  loadW1(w1a, 0);
  stageW2(0, 0);

  f32x4 accr[2][4];
  #pragma unroll
  for (int mf=0; mf<2; ++mf)
    #pragma unroll
    for (int nf=0; nf<4; ++nf) accr[mf][nf] = f32x4{0.f,0.f,0.f,0.f};

  auto body = [&](int cn, short8 (&w1c)[8], short8 (&w1n)[8]){
    const int cur = cn & 1;
    // (1) rq loads for current chunk (8 x 16B)
    float4 rc_reg[2][4];
    #pragma unroll
    for (int mf=0; mf<2; ++mf)
      #pragma unroll
      for (int r=0; r<4; ++r)
        rc_reg[mf][r] = rq[(long)(m0 + wr + mf*16 + lq*4 + r)*768 + cn*32 + wc*16 + lm];
    // (2) W1 prefetch for next chunk (8 x 16B, into the other buffer)
    if (cn < 23) loadW1(w1n, cn+1);
    // (3) wait: W2s[cur] (staged last chunk, post-barrier) resident.
    //     newer in flight: 8 rq + 8 w1n (none at cn==23)
    if (cn < 23) wait_vmcnt<16>(); else wait_vmcnt<8>();
    __builtin_amdgcn_s_barrier();
    // (4) stage W2 next AFTER the barrier: all waves have finished reading
    //     W2s[cur^1] (their last read was in chunk cn-1, before this barrier)
    if (cn < 23) stageW2(cur^1, cn+1);

    // (5) S-MFMA: 32 rows x (16 lo + 16 hi), K=128 — 16 MFMA, B-frags in regs
    f32x4 sa[2][2];   // [mf][lo/hi]
    #pragma unroll
    for (int mf=0; mf<2; ++mf)
      #pragma unroll
      for (int p=0; p<2; ++p) sa[mf][p] = f32x4{0.f,0.f,0.f,0.f};
    #pragma unroll
    for (int ks=0; ks<4; ++ks){
      sa[0][0] = __builtin_amdgcn_mfma_f32_16x16x32_bf16(af[0][ks], w1c[ks*2],   sa[0][0], 0,0,0);
      sa[0][1] = __builtin_amdgcn_mfma_f32_16x16x32_bf16(af[0][ks], w1c[ks*2+1], sa[0][1], 0,0,0);
      sa[1][0] = __builtin_amdgcn_mfma_f32_16x16x32_bf16(af[1][ks], w1c[ks*2],   sa[1][0], 0,0,0);
      sa[1][1] = __builtin_amdgcn_mfma_f32_16x16x32_bf16(af[1][ks], w1c[ks*2+1], sa[1][1], 0,0,0);
    }

    // (6) RoPE in registers; P -> wave-private LDS (local k: lo=lm, hi=16+lm)
    #pragma unroll
    for (int mf=0; mf<2; ++mf)
      #pragma unroll
      for (int r=0; r<4; ++r){
        int prow = mf*16 + lq*4 + r;
        float4 rc = rc_reg[mf][r];
        float xl = sa[mf][0][r], xh = sa[mf][1][r];
        Pp[w][prow*36 + lm]      = f2bs(xl*rc.x - xh*rc.y);
        Pp[w][prow*36 + 16 + lm] = f2bs(xh*rc.z + xl*rc.w);
      }
    asm volatile("s_waitcnt lgkmcnt(0)" ::: "memory");
    __builtin_amdgcn_sched_barrier(0);          // rule #18 fence (no s_barrier)

    // (7) PV partial: this wave's 32 k-cols x all 64 out cols, K=32 — 8 MFMA
    short8 ap[2];
    #pragma unroll
    for (int mf=0; mf<2; ++mf)
      ap[mf] = *(const short8*)&Pp[w][(mf*16 + lm)*36 + lq*8];
    const int kqsel = 2*wc + lq + ((lq>>1)<<1);  // lq<2: lo kq; lq>=2: hi kq
    #pragma unroll
    for (int nf=0; nf<4; ++nf){
      short8 bw = *(const short8*)&W2s[cur][(kqsel*64 + nf*16 + lm)*8];
      accr[0][nf] = __builtin_amdgcn_mfma_f32_16x16x32_bf16(ap[0], bw, accr[0][nf], 0,0,0);
      accr[1][nf] = __builtin_amdgcn_mfma_f32_16x16x32_bf16(ap[1], bw, accr[1][nf], 0,0,0);
    }
  };

  for (int cn = 0; cn < 24; cn += 2){
    body(cn,   w1a, w1b);
    body(cn+1, w1b, w1a);
  }

  // end: cross-wave reduction of the k-split partials (wc=1 -> wc=0)
  if (wc == 1){
    #pragma unroll
    for (int mf=0; mf<2; ++mf)
      #pragma unroll
      for (int nf=0; nf<4; ++nf)
        #pragma unroll
        for (int r=0; r<4; ++r)
          Fred[w>>1][mf*16 + lq*4 + r][nf*16 + lm] = accr[mf][nf][r];
  }
  __syncthreads();
  if (wc == 0){
    #pragma unroll
    for (int mf=0; mf<2; ++mf)
      #pragma unroll
      for (int nf=0; nf<4; ++nf)
        #pragma unroll
        for (int r=0; r<4; ++r){
          float v = accr[mf][nf][r] + Fred[w>>1][mf*16 + lq*4 + r][nf*16 + lm];
          qo[(long)(wr + mf*16 + lq*4 + r)*64 + nf*16 + lm] = f2bs(v);
        }
  }
}

// ---------------------------------------------------------------------------
// MFMA flash attention, counted-vmcnt 2-barrier K/V staging.
__global__ __launch_bounds__(256) void flash_mfma(
    const unsigned short* __restrict__ qr, const unsigned short* __restrict__ kr,
    const unsigned short* __restrict__ vt, unsigned short* __restrict__ ctx)
{
  const int b = blockIdx.z, h = blockIdx.y, s0 = blockIdx.x*64;
  const int t = threadIdx.x, w = t>>6, l = t&63;
  const int lq = l>>4, lm = l&15;

  __shared__ __align__(16) unsigned short Qs[8*64*8];
  __shared__ __align__(16) unsigned short Ks[2][8*64*8];
  __shared__ __align__(16) unsigned short Vts[2][8*128*8];
  __shared__ __align__(16) unsigned short Ps[64*72];

  const unsigned short* qbase = qr + ((long)(b*16+h)*1024 + s0)*64;
  const unsigned short* kbase = kr + (long)(b*16+h)*65536;
  const unsigned short* vbase = vt + (long)(b*16+h)*131072;

  auto stageKV = [&](int buf, int l0){
    #pragma unroll
    for (int o = 0; o < 2; ++o){
      int g = o*256 + t;
      int row = g & 63, kq = g >> 6;
      gl_lds16(kbase + (long)(l0+row)*64 + kq*8, &Ks[buf][(o*256 + w*64)*8]);
    }
    #pragma unroll
    for (int o = 0; o < 4; ++o){
      int g = o*256 + t;
      int row = g & 127, kq = g >> 7;
      gl_lds16(vbase + (long)row*1024 + l0 + kq*8, &Vts[buf][(o*256 + w*64)*8]);
    }
  };

  #pragma unroll
  for (int o = 0; o < 2; ++o){
    int g = o*256 + t;
    int row = g & 63, kq = g >> 6;
    gl_lds16(qbase + (long)row*64 + kq*8, &Qs[(o*256 + w*64)*8]);
  }
  stageKV(0, 0);
  __syncthreads();
  short8 aq[2];
  #pragma unroll
  for (int ks = 0; ks < 2; ++ks)
    aq[ks] = *(const short8*)&Qs[((ks*4+lq)*64 + w*16 + lm)*8];

  float m_run[4], l_run[4];
  #pragma unroll
  for (int r = 0; r < 4; ++r){ m_run[r] = -3e38f; l_run[r] = 0.f; }
  f32x4 acc_o[8];
  #pragma unroll
  for (int nf = 0; nf < 8; ++nf) acc_o[nf] = f32x4{0.f,0.f,0.f,0.f};

  for (int it = 0; it < 16; ++it){
    const int cur = it & 1;
    if (it < 15){ stageKV(cur^1, (it+1)*64); wait_vmcnt<6>(); }
    else        { wait_vmcnt<0>(); }
    __builtin_amdgcn_s_barrier();

    f32x4 acc_s[4];
    #pragma unroll
    for (int nf = 0; nf < 4; ++nf) acc_s[nf] = f32x4{0.f,0.f,0.f,0.f};
    #pragma unroll
    for (int ks = 0; ks < 2; ++ks)
      #pragma unroll
      for (int nf = 0; nf < 4; ++nf){
        short8 bf = *(const short8*)&Ks[cur][((ks*4+lq)*64 + nf*16 + lm)*8];
        acc_s[nf] = __builtin_amdgcn_mfma_f32_16x16x32_bf16(
            aq[ks], bf, acc_s[nf], 0, 0, 0);
      }

    float tmax[4];
    #pragma unroll
    for (int r = 0; r < 4; ++r)
      tmax[r] = fmaxf(fmaxf(acc_s[0][r], acc_s[1][r]),
                      fmaxf(acc_s[2][r], acc_s[3][r]));
    #pragma unroll
    for (int mask = 1; mask < 16; mask <<= 1)
      #pragma unroll
      for (int r = 0; r < 4; ++r)
        tmax[r] = fmaxf(tmax[r], __shfl_xor(tmax[r], mask));
    float alpha[4], rsum[4];
    #pragma unroll
    for (int r = 0; r < 4; ++r){
      float mnew = fmaxf(m_run[r], tmax[r]);
      alpha[r] = __expf(m_run[r] - mnew);
      m_run[r] = mnew;
      rsum[r] = 0.f;
    }
    #pragma unroll
    for (int nf = 0; nf < 4; ++nf)
      #pragma unroll
      for (int r = 0; r < 4; ++r){
        float p = __expf(acc_s[nf][r] - m_run[r]);
        rsum[r] += p;
        Ps[(w*16 + lq*4 + r)*72 + nf*16 + lm] = f2bs(p);
      }
    #pragma unroll
    for (int mask = 1; mask < 16; mask <<= 1)
      #pragma unroll
      for (int r = 0; r < 4; ++r)
        rsum[r] += __shfl_xor(rsum[r], mask);
    #pragma unroll
    for (int r = 0; r < 4; ++r)
      l_run[r] = l_run[r]*alpha[r] + rsum[r];

    #pragma unroll
    for (int nf = 0; nf < 8; ++nf)
      #pragma unroll
      for (int r = 0; r < 4; ++r)
        acc_o[nf][r] *= alpha[r];

    short8 ap[2];
    #pragma unroll
    for (int ks = 0; ks < 2; ++ks)
      ap[ks] = *(const short8*)&Ps[(w*16 + lm)*72 + ks*32 + lq*8];
    #pragma unroll
    for (int ks = 0; ks < 2; ++ks)
      #pragma unroll
      for (int nf = 0; nf < 8; ++nf){
        short8 bv = *(const short8*)&Vts[cur][((ks*4+lq)*128 + nf*16 + lm)*8];
        acc_o[nf] = __builtin_amdgcn_mfma_f32_16x16x32_bf16(
            ap[ks], bv, acc_o[nf], 0, 0, 0);
      }
    __builtin_amdgcn_s_barrier();   // buffer-overwrite guard (no drain)
  }

  float inv[4];
  #pragma unroll
  for (int r = 0; r < 4; ++r) inv[r] = 1.f / l_run[r];
  #pragma unroll
  for (int nf = 0; nf < 8; ++nf)
    #pragma unroll
    for (int r = 0; r < 4; ++r){
      long row = (long)b*1024 + s0 + w*16 + lq*4 + r;
      ctx[row*2048 + h*128 + nf*16 + lm] = f2bs(acc_o[nf][r]*inv[r]);
    }
}

// ---------------------------------------------------------------------------
extern "C" void kernel_launch(void* const* d_in, const int* in_sizes, int n_in,
                              void* d_out, int out_size, void* d_ws, size_t ws_size,
                              hipStream_t stream)
{
  const float* hidden_q = (const float*)d_in[0];   // [2,1024,2048]
  const float* kv_c     = (const float*)d_in[1];   // [2,1024,512]
  const float* Wq       = (const float*)d_in[2];   // [2048,2048]
  const float* w_kc_q   = (const float*)d_in[3];   // [16,128,1536]
  const float* w_kc_kv  = (const float*)d_in[4];   // [16,128,512]
  const float* W_qr     = (const float*)d_in[5];   // [16,1536,64]
  const float* W_kr     = (const float*)d_in[6];   // [16,512,64]
  const float* Wo       = (const float*)d_in[7];   // [2048,2048]
  float* out = (float*)d_out;

  char* wsb = (char*)d_ws;
  size_t off = 0;
  auto take = [&](size_t bytes)->void*{
    void* p = wsb + off; off += (bytes + 255) & ~(size_t)255; return p;
  };
  unsigned short* q_rb  = (unsigned short*)take(4194304);   // [B,H,S,64] bf16
  unsigned short* k_rb  = (unsigned short*)take(4194304);   // [B,H,L,64] bf16
  unsigned short* kv_rb = (unsigned short*)take(2097152);   // [B,L,512] bf16
  float4* ropeq4 = (float4*)take(12582912);                 // [1024][768] float4
  unsigned short* q_hk   = (unsigned short*)take(8388608);  // [B*S,2048] bf16
  unsigned short* wkcqT  = (unsigned short*)take(6291456);  // [16][1536][128] bf16
  unsigned short* WqrT   = (unsigned short*)take(3145728);  // [16][64][1536] bf16
  unsigned short* wkckvb = (unsigned short*)take(2097152);  // [16][128][512] bf16
  unsigned short* WkrT   = (unsigned short*)take(1048576);  // [16][64][512] bf16
  unsigned short* Vt     = (unsigned short*)take(8388608);  // [B,H,128,1024] bf16
  unsigned short* hiddenb = (unsigned short*)take(8388608); // bf16 hidden
  unsigned short* Wqb     = (unsigned short*)take(8388608); // bf16 Wq
  unsigned short* Wob     = (unsigned short*)take(8388608); // bf16 Wo
  unsigned short* ctx_lat = (unsigned short*)take(8388608); // [B*S,2048] bf16

  // all preprocessing (tables, k-RoPE, converts, transposes) in one launch
  prep_all<<<22528, 256, 0, stream>>>(ropeq4,
      kv_c, kv_rb,
      hidden_q, hiddenb, Wq, Wqb, w_kc_kv, wkckvb, Wo, Wob,
      w_kc_q, wkcqT, W_qr, WqrT, W_kr, WkrT);

  // 2) q_hk = hidden @ Wq^T   (2048x2048x2048) -> bf16
  gemm_mfma<128,128,64,64,unsigned short><<<dim3(16,16,1),256,0,stream>>>(
      hiddenb, Wqb, q_hk, 2048, 2048,2048,2048, 1, 0,0, 0,0, 0,0);

  // 3+4+5) q_r = RoPE(q_hk @ w_kc_q_T) @ W_qr_T, fused — 1-barrier chunks
  q_fused<<<dim3(16,1,32),256,0,stream>>>(q_hk, wkcqT, WqrT, ropeq4, q_rb);

  // 7) k_r = kv_rb @ W_kr_T  (per (b,h): 1024x64x512) -> bf16
  gemm_mfma<128,64,64,32,unsigned short><<<dim3(8,1,32),256,0,stream>>>(
      kv_rb, WkrT, k_rb, 512, 512,512,64, 16,
      524288,0, 0,32768, 1048576,65536);

  // 7b) V'^T[b,h][d][l] = w_kc_kv[h] @ kv_rb[b]^T  (per (b,h): 128x1024x512) -> bf16
  gemm_mfma<128,128,64,64,unsigned short><<<dim3(1,8,32),256,0,stream>>>(
      wkckvb, kv_rb, Vt, 512, 512,512,1024, 16,
      0,65536, 524288,0, 2097152,131072);

  // 8) MFMA flash attention -> ctx_lat bf16 [b,s][h*128+k]
  flash_mfma<<<dim3(16,16,2),256,0,stream>>>(q_rb, k_rb, Vt, ctx_lat);

  // 10) out = ctx_lat @ Wo^T  (2048x2048x2048) -> fp32
  gemm_mfma<128,128,64,64,float><<<dim3(16,16,1),256,0,stream>>>(
      ctx_lat, Wob, out, 2048, 2048,2048,2048, 1, 0,0, 0,0, 0,0);
}

// Round 9
// 333.061 us; speedup vs baseline: 1.0529x; 1.0529x over previous
//
#include <hip/hip_runtime.h>
#include <hip/hip_bf16.h>

// B=2, S=1024, L=1024, DIM_Q=2048, H=16, K=128, D_C=512, D_CQ=1536, R=64

typedef __attribute__((ext_vector_type(8))) short short8;
typedef __attribute__((ext_vector_type(4))) float f32x4;

__device__ __forceinline__ unsigned short f2bs(float v){
  __hip_bfloat16 b = __float2bfloat16(v);
  return *reinterpret_cast<unsigned short*>(&b);
}
__device__ __forceinline__ void storeC(float* p, float v){ *p = v; }
__device__ __forceinline__ void storeC(unsigned short* p, float v){ *p = f2bs(v); }

// async global->LDS, 16B per lane.  LDS dest = wave-uniform base + lane*16.
__device__ __forceinline__ void gl_lds16(const void* g, void* l){
  __builtin_amdgcn_global_load_lds(
      (const __attribute__((address_space(1))) unsigned int*)g,
      (__attribute__((address_space(3))) unsigned int*)l, 16, 0, 0);
}

// counted vmcnt wait (immediate must be a literal in the asm string)
template<int N> __device__ __forceinline__ void wait_vmcnt(){
  if constexpr (N==0)       asm volatile("s_waitcnt vmcnt(0)" ::: "memory");
  else if constexpr (N==3)  asm volatile("s_waitcnt vmcnt(3)" ::: "memory");
  else if constexpr (N==4)  asm volatile("s_waitcnt vmcnt(4)" ::: "memory");
  else if constexpr (N==6)  asm volatile("s_waitcnt vmcnt(6)" ::: "memory");
  else if constexpr (N==8)  asm volatile("s_waitcnt vmcnt(8)" ::: "memory");
  else if constexpr (N==14) asm volatile("s_waitcnt vmcnt(14)" ::: "memory");
  else if constexpr (N==16) asm volatile("s_waitcnt vmcnt(16)" ::: "memory");
  else if constexpr (N==22) asm volatile("s_waitcnt vmcnt(22)" ::: "memory");
  else static_assert(N==0, "unsupported vmcnt");
}

// ---------------------------------------------------------------------------
// transpose helper: fp32 [R,Cn] tile -> bf16 [Cn,R], one 32x32 tile per block
__device__ __forceinline__ void transpose_tile(
    const float* ip, unsigned short* op, int R, int Cn, int c0, int r0)
{
  __shared__ float tile[32][33];
  int tr = threadIdx.x>>5, tc = threadIdx.x&31;
  #pragma unroll
  for (int i=0;i<4;i++)
    tile[tr+i*8][tc] = ip[(long)(r0+tr+i*8)*Cn + c0+tc];
  __syncthreads();
  #pragma unroll
  for (int i=0;i<4;i++)
    op[(long)(c0+tr+i*8)*R + r0+tc] = f2bs(tile[tc][tr+i*8]);
}

// ---------------------------------------------------------------------------
// prep_all: packed q-RoPE table, fused k-RoPE (kv_c -> kv_rb bf16, no tables),
// 4 fp32->bf16 converts, and the 3 weight transposes — one launch.
__global__ __launch_bounds__(256) void prep_all(
    float4* __restrict__ rq,
    const float* __restrict__ kvc, unsigned short* __restrict__ kvrb,
    const float* __restrict__ hidden, unsigned short* __restrict__ hiddenb,
    const float* __restrict__ Wq, unsigned short* __restrict__ Wqb,
    const float* __restrict__ wkckv, unsigned short* __restrict__ wkckvb,
    const float* __restrict__ Wo, unsigned short* __restrict__ Wob,
    const float* __restrict__ wkcq, unsigned short* __restrict__ wkcqT,
    const float* __restrict__ Wqr, unsigned short* __restrict__ WqrT,
    const float* __restrict__ Wkr, unsigned short* __restrict__ WkrT)
{
  int blk = blockIdx.x;
  if (blk < 3072){
    int idx = blk*256 + threadIdx.x;          // < 1024*768
    int s = idx / 768, j = idx - (idx/768)*768;
    int i1 = j >> 1;                          // freq index (repeat_interleave(2))
    const float cst = -0.011992631f;          // -2*ln(10000)/1536
    float f1 = (float)s * __expf(cst * (float)i1);
    float f2 = (float)s * __expf(cst * (float)(384 + i1));
    float s1, c1, s2, c2;
    __sincosf(f1, &s1, &c1);
    __sincosf(f2, &s2, &c2);
    rq[idx] = make_float4(c1, s1, c2, s2);
    return;
  }
  if (blk < 4096){
    // fused k-RoPE: 2*1024*128 threads, 4 outputs each (pairs d,d+1,d+256,d+257)
    int idx = (blk-3072)*256 + threadIdx.x;   // < 262144
    int i1 = idx & 127;
    int l  = (idx >> 7) & 1023;
    int bb = idx >> 17;
    const float cst = -0.035977892f;          // -ln(10000)/256
    float f1 = (float)l * __expf(cst * (float)i1);
    float f2 = (float)l * __expf(cst * (float)(128 + i1));
    float s1,c1,s2,c2; __sincosf(f1,&s1,&c1); __sincosf(f2,&s2,&c2);
    long base = ((long)bb*1024 + l)*512;
    float2 xlo = *(const float2*)&kvc[base + 2*i1];
    float2 xhi = *(const float2*)&kvc[base + 2*i1 + 256];
    unsigned int lo = (unsigned)f2bs(xlo.x*c1 - xhi.x*s1)
                    | ((unsigned)f2bs(xlo.y*c1 - xhi.y*s1) << 16);
    unsigned int hi = (unsigned)f2bs(xhi.x*c2 + xlo.x*s2)
                    | ((unsigned)f2bs(xhi.y*c2 + xlo.y*s2) << 16);
    *(unsigned int*)&kvrb[base + 2*i1]       = lo;
    *(unsigned int*)&kvrb[base + 2*i1 + 256] = hi;
    return;
  }
  if (blk < 17408){
    const float* in; unsigned short* out; int i;
    if (blk < 8192){ in = hidden; out = hiddenb; i = (blk-4096)*256 + threadIdx.x; }
    else if (blk < 12288){ in = Wq; out = Wqb; i = (blk-8192)*256 + threadIdx.x; }
    else if (blk < 13312){ in = wkckv; out = wkckvb; i = (blk-12288)*256 + threadIdx.x; }
    else { in = Wo; out = Wob; i = (blk-13312)*256 + threadIdx.x; }
    float4 v = *(const float4*)(in + (long)i*4);
    ushort4 u; u.x=f2bs(v.x); u.y=f2bs(v.y); u.z=f2bs(v.z); u.w=f2bs(v.w);
    *(ushort4*)(out + (long)i*4) = u;
    return;
  }
  if (blk < 20480){            // transpose w_kc_q [16][128,1536] -> [16][1536,128]
    int b2 = blk - 17408;
    int x = b2 % 48, rem = b2 / 48, y = rem % 4, z = rem >> 2;
    transpose_tile(wkcq + (long)z*196608, wkcqT + (long)z*196608,
                   128, 1536, x*32, y*32);
    return;
  }
  if (blk < 22016){            // transpose W_qr [16][1536,64] -> [16][64,1536]
    int b2 = blk - 20480;
    int x = b2 & 1, rem = b2 >> 1, y = rem % 48, z = rem / 48;
    transpose_tile(Wqr + (long)z*98304, WqrT + (long)z*98304,
                   1536, 64, x*32, y*32);
    return;
  }
  {                            // transpose W_kr [16][512,64] -> [16][64,512]
    int b2 = blk - 22016;
    int x = b2 & 1, y = (b2 >> 1) & 15, z = b2 >> 5;
    transpose_tile(Wkr + (long)z*32768, WkrT + (long)z*32768,
                   512, 64, x*32, y*32);
  }
}

// ---------------------------------------------------------------------------
// bf16 MFMA GEMM (NT), 4-buffer LDS pipeline with counted vmcnt.
template<int BM,int BN,int WM,int WN,typename TC>
__global__ __launch_bounds__(256) void gemm_mfma(
    const unsigned short* __restrict__ A, const unsigned short* __restrict__ B,
    TC* __restrict__ C,
    int Kd, int lda, int ldb, int ldc, int Hb,
    long sAb, long sAh, long sBb, long sBh, long sCb, long sCh)
{
  constexpr int MF = WM/16, NF = WN/16;
  constexpr int WGM = BM/WM;
  constexpr int AOPS = (4*BM)/256;
  constexpr int BOPS = (4*BN)/256;
  constexpr int STG  = AOPS + BOPS;   // gl_lds16 per thread per stage

  const int z = blockIdx.z, bb = z/Hb, hh = z - bb*Hb;
  const unsigned short* Ap = A + bb*sAb + hh*sAh;
  const unsigned short* Bp = B + bb*sBb + hh*sBh;
  TC* Cp = C + bb*sCb + hh*sCh;
  const int m0 = blockIdx.x*BM, n0 = blockIdx.y*BN;
  const int t = threadIdx.x, w = t>>6, l = t&63;
  const int wm0 = (w % WGM)*WM, wn0 = (w / WGM)*WN;
  const int lq = l>>4, lm = l&15;

  __shared__ __align__(16) unsigned short As[4][4*BM*8];
  __shared__ __align__(16) unsigned short Bs[4][4*BN*8];

  f32x4 acc[MF][NF];
  #pragma unroll
  for (int mf=0; mf<MF; ++mf)
    #pragma unroll
    for (int nf=0; nf<NF; ++nf)
      acc[mf][nf] = f32x4{0.f,0.f,0.f,0.f};

  auto stage = [&](int buf, int k0){
    #pragma unroll
    for (int o = 0; o < AOPS; ++o){
      int g = o*256 + t;
      int row = g & (BM-1), kq = g / BM;
      gl_lds16(Ap + (long)(m0+row)*lda + k0 + kq*8, &As[buf][(o*256 + w*64)*8]);
    }
    #pragma unroll
    for (int o = 0; o < BOPS; ++o){
      int g = o*256 + t;
      int row = g & (BN-1), kq = g / BN;
      gl_lds16(Bp + (long)(n0+row)*ldb + k0 + kq*8, &Bs[buf][(o*256 + w*64)*8]);
    }
  };

  const int nIter = Kd >> 5;
  stage(0, 0);
  if (1 < nIter) stage(1, 32);
  if (2 < nIter) stage(2, 64);

  for (int it = 0; it < nIter; ++it){
    const int cur = it & 3;
    const int rem = nIter - it;
    if (rem >= 3)      wait_vmcnt<2*STG>();
    else if (rem == 2) wait_vmcnt<STG>();
    else               wait_vmcnt<0>();
    __builtin_amdgcn_s_barrier();

    short8 af[MF], bfr[NF];
    #pragma unroll
    for (int mf=0; mf<MF; ++mf)
      af[mf] = *(const short8*)&As[cur][(lq*BM + wm0 + mf*16 + lm)*8];
    #pragma unroll
    for (int nf=0; nf<NF; ++nf)
      bfr[nf] = *(const short8*)&Bs[cur][(lq*BN + wn0 + nf*16 + lm)*8];
    #pragma unroll
    for (int mf=0; mf<MF; ++mf)
      #pragma unroll
      for (int nf=0; nf<NF; ++nf)
        acc[mf][nf] = __builtin_amdgcn_mfma_f32_16x16x32_bf16(
            af[mf], bfr[nf], acc[mf][nf], 0, 0, 0);

    if (it+3 < nIter) stage((it+3) & 3, (it+3)*32);
  }

  #pragma unroll
  for (int mf=0; mf<MF; ++mf){
    #pragma unroll
    for (int nf=0; nf<NF; ++nf){
      int row = m0 + wm0 + mf*16 + lq*4;
      int col = n0 + wn0 + nf*16 + lm;
      #pragma unroll
      for (int r=0; r<4; ++r)
        storeC(&Cp[(long)(row+r)*ldc + col], acc[mf][nf][r]);
    }
  }
}

// ---------------------------------------------------------------------------
// q_fused v6: BM=64, 512 blocks (2/CU).  ONE barrier per chunk, cooperative
// LDS staging (r6's W1+W2 gl_lds, issued POST-barrier), k-split PV with
// wave-private P (r8, passed), rq table double-buffered in registers
// (prefetch cn+1 at top of cn -> L3 latency off the critical path).
// vmcnt at chunk cn: outstanding = rq(cn)[8 oldest] + stage(cn)[6] +
// rq(cn+1)[8 newest] -> vmcnt(8) drains stage+old-rq.  cn=23: vmcnt(0).
__global__ __launch_bounds__(256) void q_fused(
    const unsigned short* __restrict__ A,    // q_hk [2048][2048]
    const unsigned short* __restrict__ W1t,  // wkcqT [16][1536][128]
    const unsigned short* __restrict__ W2t,  // WqrT  [16][64][1536]
    const float4* __restrict__ rq,           // [1024][768]
    unsigned short* __restrict__ qrOut)      // q_rb [B,H,1024,64]
{
  const int z = blockIdx.z, bb = z>>4, hh = z&15;
  const int m0 = blockIdx.x*64;
  const unsigned short* Ap = A + (long)bb*2097152 + hh*128;   // row stride 2048
  const unsigned short* W1 = W1t + (long)hh*196608;           // [1536][128]
  const unsigned short* W2 = W2t + (long)hh*98304;            // [64][1536]
  unsigned short* qo = qrOut + ((long)z*1024 + m0)*64;

  const int t = threadIdx.x, w = t>>6, l = t&63;
  const int lq = l>>4, lm = l&15;
  const int wr = (w>>1)*32;      // wave row-block
  const int wc = w&1;            // wave col-half

  __shared__ __align__(16) unsigned short W1s[2][16*64*8];  // 32 KB
  __shared__ __align__(16) unsigned short W2s[2][8*64*8];   // 16 KB
  __shared__ __align__(16) unsigned short Pp[4][32*36];     // 9 KB (wave-private)
  __shared__ float Fred[2][32][64];                         // 16 KB (end reduce)

  // A fragments once from global (L2/L3-resident): af[mf][ks]  (r8, passed)
  short8 af[2][4];
  #pragma unroll
  for (int mf=0; mf<2; ++mf)
    #pragma unroll
    for (int ks=0; ks<4; ++ks)
      af[mf][ks] = *(const short8*)&Ap[(long)(m0 + wr + mf*16 + lm)*2048 + (ks*4+lq)*8];

  // cooperative staging (r6's exact indices): 4 W1 + 2 W2 gl_lds per thread
  auto stageW = [&](int buf, int cn){
    #pragma unroll
    for (int o=0;o<4;++o){
      int g=o*256+t; int row=g&63, kq=g>>6;
      int grow = (row<32) ? (cn*32+row) : (736+cn*32+row);   // row>=32: 768+(row-32)
      gl_lds16(W1 + (long)grow*128 + kq*8, &W1s[buf][(o*256+w*64)*8]);
    }
    #pragma unroll
    for (int o=0;o<2;++o){
      int g=o*256+t; int n=g&63, kq=g>>6;
      int qk = (kq<4) ? (cn*32+kq*8) : (736+cn*32+kq*8);     // kq>=4: 768+(kq-4)*8
      gl_lds16(W2 + (long)n*1536 + qk, &W2s[buf][(o*256+w*64)*8]);
    }
  };
  auto loadRQ = [&](float4 (&rc)[2][4], int cn){
    #pragma unroll
    for (int mf=0; mf<2; ++mf)
      #pragma unroll
      for (int r=0; r<4; ++r)
        rc[mf][r] = rq[(long)(m0 + wr + mf*16 + lq*4 + r)*768 + cn*32 + wc*16 + lm];
  };

  stageW(0, 0);
  float4 rc_a[2][4], rc_b[2][4];
  loadRQ(rc_a, 0);

  f32x4 accr[2][4];
  #pragma unroll
  for (int mf=0; mf<2; ++mf)
    #pragma unroll
    for (int nf=0; nf<4; ++nf) accr[mf][nf] = f32x4{0.f,0.f,0.f,0.f};

  auto body = [&](int cn, float4 (&rcc)[2][4], float4 (&rcn)[2][4]){
    const int cur = cn & 1;
    // (1) rq prefetch for NEXT chunk (8 loads, newest in flight)
    if (cn < 23) loadRQ(rcn, cn+1);
    // (2) wait: stage(cn) resident (drains old rq too); cn=23 has no newer
    if (cn < 23) wait_vmcnt<8>(); else wait_vmcnt<0>();
    __builtin_amdgcn_s_barrier();
    // (3) stage NEXT chunk post-barrier (overwrite-safe: all waves finished
    //     reading buf cur^1 in chunk cn-1, before this barrier)
    if (cn < 23) stageW(cur^1, cn+1);

    // (4) S-MFMA: 32 rows x (16 lo + 16 hi), K=128 — 8 LDS frag reads, 16 MFMA
    f32x4 sa[2][2];   // [mf][lo/hi]
    #pragma unroll
    for (int mf=0; mf<2; ++mf)
      #pragma unroll
      for (int p=0; p<2; ++p) sa[mf][p] = f32x4{0.f,0.f,0.f,0.f};
    #pragma unroll
    for (int ks=0; ks<4; ++ks){
      short8 blo = *(const short8*)&W1s[cur][((ks*4+lq)*64 + wc*16 + lm)*8];
      short8 bhi = *(const short8*)&W1s[cur][((ks*4+lq)*64 + 32 + wc*16 + lm)*8];
      sa[0][0] = __builtin_amdgcn_mfma_f32_16x16x32_bf16(af[0][ks], blo, sa[0][0], 0,0,0);
      sa[0][1] = __builtin_amdgcn_mfma_f32_16x16x32_bf16(af[0][ks], bhi, sa[0][1], 0,0,0);
      sa[1][0] = __builtin_amdgcn_mfma_f32_16x16x32_bf16(af[1][ks], blo, sa[1][0], 0,0,0);
      sa[1][1] = __builtin_amdgcn_mfma_f32_16x16x32_bf16(af[1][ks], bhi, sa[1][1], 0,0,0);
    }

    // (5) RoPE in registers (rcc prefetched last chunk — no VMEM stall);
    //     P -> wave-private LDS (local k: lo=lm, hi=16+lm)
    #pragma unroll
    for (int mf=0; mf<2; ++mf)
      #pragma unroll
      for (int r=0; r<4; ++r){
        int prow = mf*16 + lq*4 + r;
        float4 rc = rcc[mf][r];
        float xl = sa[mf][0][r], xh = sa[mf][1][r];
        Pp[w][prow*36 + lm]      = f2bs(xl*rc.x - xh*rc.y);
        Pp[w][prow*36 + 16 + lm] = f2bs(xh*rc.z + xl*rc.w);
      }
    asm volatile("s_waitcnt lgkmcnt(0)" ::: "memory");
    __builtin_amdgcn_sched_barrier(0);          // rule #18 fence (no s_barrier)

    // (6) PV partial: this wave's 32 k-cols x all 64 out cols, K=32 — 8 MFMA
    short8 ap[2];
    #pragma unroll
    for (int mf=0; mf<2; ++mf)
      ap[mf] = *(const short8*)&Pp[w][(mf*16 + lm)*36 + lq*8];
    const int kqsel = 2*wc + lq + ((lq>>1)<<1);  // r8's mapping (passed)
    #pragma unroll
    for (int nf=0; nf<4; ++nf){
      short8 bw = *(const short8*)&W2s[cur][(kqsel*64 + nf*16 + lm)*8];
      accr[0][nf] = __builtin_amdgcn_mfma_f32_16x16x32_bf16(ap[0], bw, accr[0][nf], 0,0,0);
      accr[1][nf] = __builtin_amdgcn_mfma_f32_16x16x32_bf16(ap[1], bw, accr[1][nf], 0,0,0);
    }
  };

  for (int cn = 0; cn < 24; cn += 2){
    body(cn,   rc_a, rc_b);
    body(cn+1, rc_b, rc_a);
  }

  // end: cross-wave reduction of the k-split partials (wc=1 -> wc=0)
  if (wc == 1){
    #pragma unroll
    for (int mf=0; mf<2; ++mf)
      #pragma unroll
      for (int nf=0; nf<4; ++nf)
        #pragma unroll
        for (int r=0; r<4; ++r)
          Fred[w>>1][mf*16 + lq*4 + r][nf*16 + lm] = accr[mf][nf][r];
  }
  __syncthreads();
  if (wc == 0){
    #pragma unroll
    for (int mf=0; mf<2; ++mf)
      #pragma unroll
      for (int nf=0; nf<4; ++nf)
        #pragma unroll
        for (int r=0; r<4; ++r){
          float v = accr[mf][nf][r] + Fred[w>>1][mf*16 + lq*4 + r][nf*16 + lm];
          qo[(long)(wr + mf*16 + lq*4 + r)*64 + nf*16 + lm] = f2bs(v);
        }
  }
}

// ---------------------------------------------------------------------------
// MFMA flash attention, counted-vmcnt 2-barrier K/V staging.
__global__ __launch_bounds__(256) void flash_mfma(
    const unsigned short* __restrict__ qr, const unsigned short* __restrict__ kr,
    const unsigned short* __restrict__ vt, unsigned short* __restrict__ ctx)
{
  const int b = blockIdx.z, h = blockIdx.y, s0 = blockIdx.x*64;
  const int t = threadIdx.x, w = t>>6, l = t&63;
  const int lq = l>>4, lm = l&15;

  __shared__ __align__(16) unsigned short Qs[8*64*8];
  __shared__ __align__(16) unsigned short Ks[2][8*64*8];
  __shared__ __align__(16) unsigned short Vts[2][8*128*8];
  __shared__ __align__(16) unsigned short Ps[64*72];

  const unsigned short* qbase = qr + ((long)(b*16+h)*1024 + s0)*64;
  const unsigned short* kbase = kr + (long)(b*16+h)*65536;
  const unsigned short* vbase = vt + (long)(b*16+h)*131072;

  auto stageKV = [&](int buf, int l0){
    #pragma unroll
    for (int o = 0; o < 2; ++o){
      int g = o*256 + t;
      int row = g & 63, kq = g >> 6;
      gl_lds16(kbase + (long)(l0+row)*64 + kq*8, &Ks[buf][(o*256 + w*64)*8]);
    }
    #pragma unroll
    for (int o = 0; o < 4; ++o){
      int g = o*256 + t;
      int row = g & 127, kq = g >> 7;
      gl_lds16(vbase + (long)row*1024 + l0 + kq*8, &Vts[buf][(o*256 + w*64)*8]);
    }
  };

  #pragma unroll
  for (int o = 0; o < 2; ++o){
    int g = o*256 + t;
    int row = g & 63, kq = g >> 6;
    gl_lds16(qbase + (long)row*64 + kq*8, &Qs[(o*256 + w*64)*8]);
  }
  stageKV(0, 0);
  __syncthreads();
  short8 aq[2];
  #pragma unroll
  for (int ks = 0; ks < 2; ++ks)
    aq[ks] = *(const short8*)&Qs[((ks*4+lq)*64 + w*16 + lm)*8];

  float m_run[4], l_run[4];
  #pragma unroll
  for (int r = 0; r < 4; ++r){ m_run[r] = -3e38f; l_run[r] = 0.f; }
  f32x4 acc_o[8];
  #pragma unroll
  for (int nf = 0; nf < 8; ++nf) acc_o[nf] = f32x4{0.f,0.f,0.f,0.f};

  for (int it = 0; it < 16; ++it){
    const int cur = it & 1;
    if (it < 15){ stageKV(cur^1, (it+1)*64); wait_vmcnt<6>(); }
    else        { wait_vmcnt<0>(); }
    __builtin_amdgcn_s_barrier();

    f32x4 acc_s[4];
    #pragma unroll
    for (int nf = 0; nf < 4; ++nf) acc_s[nf] = f32x4{0.f,0.f,0.f,0.f};
    #pragma unroll
    for (int ks = 0; ks < 2; ++ks)
      #pragma unroll
      for (int nf = 0; nf < 4; ++nf){
        short8 bf = *(const short8*)&Ks[cur][((ks*4+lq)*64 + nf*16 + lm)*8];
        acc_s[nf] = __builtin_amdgcn_mfma_f32_16x16x32_bf16(
            aq[ks], bf, acc_s[nf], 0, 0, 0);
      }

    float tmax[4];
    #pragma unroll
    for (int r = 0; r < 4; ++r)
      tmax[r] = fmaxf(fmaxf(acc_s[0][r], acc_s[1][r]),
                      fmaxf(acc_s[2][r], acc_s[3][r]));
    #pragma unroll
    for (int mask = 1; mask < 16; mask <<= 1)
      #pragma unroll
      for (int r = 0; r < 4; ++r)
        tmax[r] = fmaxf(tmax[r], __shfl_xor(tmax[r], mask));
    float alpha[4], rsum[4];
    #pragma unroll
    for (int r = 0; r < 4; ++r){
      float mnew = fmaxf(m_run[r], tmax[r]);
      alpha[r] = __expf(m_run[r] - mnew);
      m_run[r] = mnew;
      rsum[r] = 0.f;
    }
    #pragma unroll
    for (int nf = 0; nf < 4; ++nf)
      #pragma unroll
      for (int r = 0; r < 4; ++r){
        float p = __expf(acc_s[nf][r] - m_run[r]);
        rsum[r] += p;
        Ps[(w*16 + lq*4 + r)*72 + nf*16 + lm] = f2bs(p);
      }
    #pragma unroll
    for (int mask = 1; mask < 16; mask <<= 1)
      #pragma unroll
      for (int r = 0; r < 4; ++r)
        rsum[r] += __shfl_xor(rsum[r], mask);
    #pragma unroll
    for (int r = 0; r < 4; ++r)
      l_run[r] = l_run[r]*alpha[r] + rsum[r];

    #pragma unroll
    for (int nf = 0; nf < 8; ++nf)
      #pragma unroll
      for (int r = 0; r < 4; ++r)
        acc_o[nf][r] *= alpha[r];

    short8 ap[2];
    #pragma unroll
    for (int ks = 0; ks < 2; ++ks)
      ap[ks] = *(const short8*)&Ps[(w*16 + lm)*72 + ks*32 + lq*8];
    #pragma unroll
    for (int ks = 0; ks < 2; ++ks)
      #pragma unroll
      for (int nf = 0; nf < 8; ++nf){
        short8 bv = *(const short8*)&Vts[cur][((ks*4+lq)*128 + nf*16 + lm)*8];
        acc_o[nf] = __builtin_amdgcn_mfma_f32_16x16x32_bf16(
            ap[ks], bv, acc_o[nf], 0, 0, 0);
      }
    __builtin_amdgcn_s_barrier();   // buffer-overwrite guard (no drain)
  }

  float inv[4];
  #pragma unroll
  for (int r = 0; r < 4; ++r) inv[r] = 1.f / l_run[r];
  #pragma unroll
  for (int nf = 0; nf < 8; ++nf)
    #pragma unroll
    for (int r = 0; r < 4; ++r){
      long row = (long)b*1024 + s0 + w*16 + lq*4 + r;
      ctx[row*2048 + h*128 + nf*16 + lm] = f2bs(acc_o[nf][r]*inv[r]);
    }
}

// ---------------------------------------------------------------------------
extern "C" void kernel_launch(void* const* d_in, const int* in_sizes, int n_in,
                              void* d_out, int out_size, void* d_ws, size_t ws_size,
                              hipStream_t stream)
{
  const float* hidden_q = (const float*)d_in[0];   // [2,1024,2048]
  const float* kv_c     = (const float*)d_in[1];   // [2,1024,512]
  const float* Wq       = (const float*)d_in[2];   // [2048,2048]
  const float* w_kc_q   = (const float*)d_in[3];   // [16,128,1536]
  const float* w_kc_kv  = (const float*)d_in[4];   // [16,128,512]
  const float* W_qr     = (const float*)d_in[5];   // [16,1536,64]
  const float* W_kr     = (const float*)d_in[6];   // [16,512,64]
  const float* Wo       = (const float*)d_in[7];   // [2048,2048]
  float* out = (float*)d_out;

  char* wsb = (char*)d_ws;
  size_t off = 0;
  auto take = [&](size_t bytes)->void*{
    void* p = wsb + off; off += (bytes + 255) & ~(size_t)255; return p;
  };
  unsigned short* q_rb  = (unsigned short*)take(4194304);   // [B,H,S,64] bf16
  unsigned short* k_rb  = (unsigned short*)take(4194304);   // [B,H,L,64] bf16
  unsigned short* kv_rb = (unsigned short*)take(2097152);   // [B,L,512] bf16
  float4* ropeq4 = (float4*)take(12582912);                 // [1024][768] float4
  unsigned short* q_hk   = (unsigned short*)take(8388608);  // [B*S,2048] bf16
  unsigned short* wkcqT  = (unsigned short*)take(6291456);  // [16][1536][128] bf16
  unsigned short* WqrT   = (unsigned short*)take(3145728);  // [16][64][1536] bf16
  unsigned short* wkckvb = (unsigned short*)take(2097152);  // [16][128][512] bf16
  unsigned short* WkrT   = (unsigned short*)take(1048576);  // [16][64][512] bf16
  unsigned short* Vt     = (unsigned short*)take(8388608);  // [B,H,128,1024] bf16
  unsigned short* hiddenb = (unsigned short*)take(8388608); // bf16 hidden
  unsigned short* Wqb     = (unsigned short*)take(8388608); // bf16 Wq
  unsigned short* Wob     = (unsigned short*)take(8388608); // bf16 Wo
  unsigned short* ctx_lat = (unsigned short*)take(8388608); // [B*S,2048] bf16

  // all preprocessing (tables, k-RoPE, converts, transposes) in one launch
  prep_all<<<22528, 256, 0, stream>>>(ropeq4,
      kv_c, kv_rb,
      hidden_q, hiddenb, Wq, Wqb, w_kc_kv, wkckvb, Wo, Wob,
      w_kc_q, wkcqT, W_qr, WqrT, W_kr, WkrT);

  // 2) q_hk = hidden @ Wq^T   (2048x2048x2048) -> bf16
  gemm_mfma<128,128,64,64,unsigned short><<<dim3(16,16,1),256,0,stream>>>(
      hiddenb, Wqb, q_hk, 2048, 2048,2048,2048, 1, 0,0, 0,0, 0,0);

  // 3+4+5) q_r = RoPE(q_hk @ w_kc_q_T) @ W_qr_T, fused — v6: 1 barrier/chunk
  q_fused<<<dim3(16,1,32),256,0,stream>>>(q_hk, wkcqT, WqrT, ropeq4, q_rb);

  // 7) k_r = kv_rb @ W_kr_T  (per (b,h): 1024x64x512) -> bf16
  gemm_mfma<128,64,64,32,unsigned short><<<dim3(8,1,32),256,0,stream>>>(
      kv_rb, WkrT, k_rb, 512, 512,512,64, 16,
      524288,0, 0,32768, 1048576,65536);

  // 7b) V'^T[b,h][d][l] = w_kc_kv[h] @ kv_rb[b]^T  (per (b,h): 128x1024x512) -> bf16
  gemm_mfma<128,128,64,64,unsigned short><<<dim3(1,8,32),256,0,stream>>>(
      wkckvb, kv_rb, Vt, 512, 512,512,1024, 16,
      0,65536, 524288,0, 2097152,131072);

  // 8) MFMA flash attention -> ctx_lat bf16 [b,s][h*128+k]
  flash_mfma<<<dim3(16,16,2),256,0,stream>>>(q_rb, k_rb, Vt, ctx_lat);

  // 10) out = ctx_lat @ Wo^T  (2048x2048x2048) -> fp32
  gemm_mfma<128,128,64,64,float><<<dim3(16,16,1),256,0,stream>>>(
      ctx_lat, Wob, out, 2048, 2048,2048,2048, 1, 0,0, 0,0, 0,0);
}

// Round 10
// 320.909 us; speedup vs baseline: 1.0927x; 1.0379x over previous
//
#include <hip/hip_runtime.h>
#include <hip/hip_bf16.h>

// B=2, S=1024, L=1024, DIM_Q=2048, H=16, K=128, D_C=512, D_CQ=1536, R=64

typedef __attribute__((ext_vector_type(8))) short short8;
typedef __attribute__((ext_vector_type(4))) float f32x4;

__device__ __forceinline__ unsigned short f2bs(float v){
  __hip_bfloat16 b = __float2bfloat16(v);
  return *reinterpret_cast<unsigned short*>(&b);
}
__device__ __forceinline__ void storeC(float* p, float v){ *p = v; }
__device__ __forceinline__ void storeC(unsigned short* p, float v){ *p = f2bs(v); }

// async global->LDS, 16B per lane.  LDS dest = wave-uniform base + lane*16.
__device__ __forceinline__ void gl_lds16(const void* g, void* l){
  __builtin_amdgcn_global_load_lds(
      (const __attribute__((address_space(1))) unsigned int*)g,
      (__attribute__((address_space(3))) unsigned int*)l, 16, 0, 0);
}

// counted vmcnt wait (immediate must be a literal in the asm string)
template<int N> __device__ __forceinline__ void wait_vmcnt(){
  if constexpr (N==0)       asm volatile("s_waitcnt vmcnt(0)" ::: "memory");
  else if constexpr (N==3)  asm volatile("s_waitcnt vmcnt(3)" ::: "memory");
  else if constexpr (N==4)  asm volatile("s_waitcnt vmcnt(4)" ::: "memory");
  else if constexpr (N==6)  asm volatile("s_waitcnt vmcnt(6)" ::: "memory");
  else if constexpr (N==8)  asm volatile("s_waitcnt vmcnt(8)" ::: "memory");
  else if constexpr (N==14) asm volatile("s_waitcnt vmcnt(14)" ::: "memory");
  else if constexpr (N==16) asm volatile("s_waitcnt vmcnt(16)" ::: "memory");
  else if constexpr (N==22) asm volatile("s_waitcnt vmcnt(22)" ::: "memory");
  else static_assert(N==0, "unsupported vmcnt");
}

// ---------------------------------------------------------------------------
// transpose helper: fp32 [R,Cn] tile -> bf16 [Cn,R], one 32x32 tile per block
__device__ __forceinline__ void transpose_tile(
    const float* ip, unsigned short* op, int R, int Cn, int c0, int r0)
{
  __shared__ float tile[32][33];
  int tr = threadIdx.x>>5, tc = threadIdx.x&31;
  #pragma unroll
  for (int i=0;i<4;i++)
    tile[tr+i*8][tc] = ip[(long)(r0+tr+i*8)*Cn + c0+tc];
  __syncthreads();
  #pragma unroll
  for (int i=0;i<4;i++)
    op[(long)(c0+tr+i*8)*R + r0+tc] = f2bs(tile[tc][tr+i*8]);
}

// ---------------------------------------------------------------------------
// prep_all: packed q-RoPE table, fused k-RoPE (kv_c -> kv_rb bf16, no tables),
// 4 fp32->bf16 converts, and the 3 weight transposes — one launch.
__global__ __launch_bounds__(256) void prep_all(
    float4* __restrict__ rq,
    const float* __restrict__ kvc, unsigned short* __restrict__ kvrb,
    const float* __restrict__ hidden, unsigned short* __restrict__ hiddenb,
    const float* __restrict__ Wq, unsigned short* __restrict__ Wqb,
    const float* __restrict__ wkckv, unsigned short* __restrict__ wkckvb,
    const float* __restrict__ Wo, unsigned short* __restrict__ Wob,
    const float* __restrict__ wkcq, unsigned short* __restrict__ wkcqT,
    const float* __restrict__ Wqr, unsigned short* __restrict__ WqrT,
    const float* __restrict__ Wkr, unsigned short* __restrict__ WkrT)
{
  int blk = blockIdx.x;
  if (blk < 3072){
    int idx = blk*256 + threadIdx.x;          // < 1024*768
    int s = idx / 768, j = idx - (idx/768)*768;
    int i1 = j >> 1;                          // freq index (repeat_interleave(2))
    const float cst = -0.011992631f;          // -2*ln(10000)/1536
    float f1 = (float)s * __expf(cst * (float)i1);
    float f2 = (float)s * __expf(cst * (float)(384 + i1));
    float s1, c1, s2, c2;
    __sincosf(f1, &s1, &c1);
    __sincosf(f2, &s2, &c2);
    rq[idx] = make_float4(c1, s1, c2, s2);
    return;
  }
  if (blk < 4096){
    // fused k-RoPE: 2*1024*128 threads, 4 outputs each (pairs d,d+1,d+256,d+257)
    int idx = (blk-3072)*256 + threadIdx.x;   // < 262144
    int i1 = idx & 127;
    int l  = (idx >> 7) & 1023;
    int bb = idx >> 17;
    const float cst = -0.035977892f;          // -ln(10000)/256
    float f1 = (float)l * __expf(cst * (float)i1);
    float f2 = (float)l * __expf(cst * (float)(128 + i1));
    float s1,c1,s2,c2; __sincosf(f1,&s1,&c1); __sincosf(f2,&s2,&c2);
    long base = ((long)bb*1024 + l)*512;
    float2 xlo = *(const float2*)&kvc[base + 2*i1];
    float2 xhi = *(const float2*)&kvc[base + 2*i1 + 256];
    unsigned int lo = (unsigned)f2bs(xlo.x*c1 - xhi.x*s1)
                    | ((unsigned)f2bs(xlo.y*c1 - xhi.y*s1) << 16);
    unsigned int hi = (unsigned)f2bs(xhi.x*c2 + xlo.x*s2)
                    | ((unsigned)f2bs(xhi.y*c2 + xlo.y*s2) << 16);
    *(unsigned int*)&kvrb[base + 2*i1]       = lo;
    *(unsigned int*)&kvrb[base + 2*i1 + 256] = hi;
    return;
  }
  if (blk < 17408){
    const float* in; unsigned short* out; int i;
    if (blk < 8192){ in = hidden; out = hiddenb; i = (blk-4096)*256 + threadIdx.x; }
    else if (blk < 12288){ in = Wq; out = Wqb; i = (blk-8192)*256 + threadIdx.x; }
    else if (blk < 13312){ in = wkckv; out = wkckvb; i = (blk-12288)*256 + threadIdx.x; }
    else { in = Wo; out = Wob; i = (blk-13312)*256 + threadIdx.x; }
    float4 v = *(const float4*)(in + (long)i*4);
    ushort4 u; u.x=f2bs(v.x); u.y=f2bs(v.y); u.z=f2bs(v.z); u.w=f2bs(v.w);
    *(ushort4*)(out + (long)i*4) = u;
    return;
  }
  if (blk < 20480){            // transpose w_kc_q [16][128,1536] -> [16][1536,128]
    int b2 = blk - 17408;
    int x = b2 % 48, rem = b2 / 48, y = rem % 4, z = rem >> 2;
    transpose_tile(wkcq + (long)z*196608, wkcqT + (long)z*196608,
                   128, 1536, x*32, y*32);
    return;
  }
  if (blk < 22016){            // transpose W_qr [16][1536,64] -> [16][64,1536]
    int b2 = blk - 20480;
    int x = b2 & 1, rem = b2 >> 1, y = rem % 48, z = rem / 48;
    transpose_tile(Wqr + (long)z*98304, WqrT + (long)z*98304,
                   1536, 64, x*32, y*32);
    return;
  }
  {                            // transpose W_kr [16][512,64] -> [16][64,512]
    int b2 = blk - 22016;
    int x = b2 & 1, y = (b2 >> 1) & 15, z = b2 >> 5;
    transpose_tile(Wkr + (long)z*32768, WkrT + (long)z*32768,
                   512, 64, x*32, y*32);
  }
}

// ---------------------------------------------------------------------------
// bf16 MFMA GEMM (NT), 4-buffer LDS pipeline with counted vmcnt (template,
// used for the final fp32-out GEMM).
template<int BM,int BN,int WM,int WN,typename TC>
__global__ __launch_bounds__(256) void gemm_mfma(
    const unsigned short* __restrict__ A, const unsigned short* __restrict__ B,
    TC* __restrict__ C,
    int Kd, int lda, int ldb, int ldc, int Hb,
    long sAb, long sAh, long sBb, long sBh, long sCb, long sCh)
{
  constexpr int MF = WM/16, NF = WN/16;
  constexpr int WGM = BM/WM;
  constexpr int AOPS = (4*BM)/256;
  constexpr int BOPS = (4*BN)/256;
  constexpr int STG  = AOPS + BOPS;   // gl_lds16 per thread per stage

  const int z = blockIdx.z, bb = z/Hb, hh = z - bb*Hb;
  const unsigned short* Ap = A + bb*sAb + hh*sAh;
  const unsigned short* Bp = B + bb*sBb + hh*sBh;
  TC* Cp = C + bb*sCb + hh*sCh;
  const int m0 = blockIdx.x*BM, n0 = blockIdx.y*BN;
  const int t = threadIdx.x, w = t>>6, l = t&63;
  const int wm0 = (w % WGM)*WM, wn0 = (w / WGM)*WN;
  const int lq = l>>4, lm = l&15;

  __shared__ __align__(16) unsigned short As[4][4*BM*8];
  __shared__ __align__(16) unsigned short Bs[4][4*BN*8];

  f32x4 acc[MF][NF];
  #pragma unroll
  for (int mf=0; mf<MF; ++mf)
    #pragma unroll
    for (int nf=0; nf<NF; ++nf)
      acc[mf][nf] = f32x4{0.f,0.f,0.f,0.f};

  auto stage = [&](int buf, int k0){
    #pragma unroll
    for (int o = 0; o < AOPS; ++o){
      int g = o*256 + t;
      int row = g & (BM-1), kq = g / BM;
      gl_lds16(Ap + (long)(m0+row)*lda + k0 + kq*8, &As[buf][(o*256 + w*64)*8]);
    }
    #pragma unroll
    for (int o = 0; o < BOPS; ++o){
      int g = o*256 + t;
      int row = g & (BN-1), kq = g / BN;
      gl_lds16(Bp + (long)(n0+row)*ldb + k0 + kq*8, &Bs[buf][(o*256 + w*64)*8]);
    }
  };

  const int nIter = Kd >> 5;
  stage(0, 0);
  if (1 < nIter) stage(1, 32);
  if (2 < nIter) stage(2, 64);

  for (int it = 0; it < nIter; ++it){
    const int cur = it & 3;
    const int rem = nIter - it;
    if (rem >= 3)      wait_vmcnt<2*STG>();
    else if (rem == 2) wait_vmcnt<STG>();
    else               wait_vmcnt<0>();
    __builtin_amdgcn_s_barrier();

    short8 af[MF], bfr[NF];
    #pragma unroll
    for (int mf=0; mf<MF; ++mf)
      af[mf] = *(const short8*)&As[cur][(lq*BM + wm0 + mf*16 + lm)*8];
    #pragma unroll
    for (int nf=0; nf<NF; ++nf)
      bfr[nf] = *(const short8*)&Bs[cur][(lq*BN + wn0 + nf*16 + lm)*8];
    #pragma unroll
    for (int mf=0; mf<MF; ++mf)
      #pragma unroll
      for (int nf=0; nf<NF; ++nf)
        acc[mf][nf] = __builtin_amdgcn_mfma_f32_16x16x32_bf16(
            af[mf], bfr[nf], acc[mf][nf], 0, 0, 0);

    if (it+3 < nIter) stage((it+3) & 3, (it+3)*32);
  }

  #pragma unroll
  for (int mf=0; mf<MF; ++mf){
    #pragma unroll
    for (int nf=0; nf<NF; ++nf){
      int row = m0 + wm0 + mf*16 + lq*4;
      int col = n0 + wn0 + nf*16 + lm;
      #pragma unroll
      for (int r=0; r<4; ++r)
        storeC(&Cp[(long)(row+r)*ldc + col], acc[mf][nf][r]);
    }
  }
}

// ---------------------------------------------------------------------------
// gemm_merged: THREE independent bf16 GEMMs (q_hk, k_r-as-one-GEMM, Vt) in a
// single 640-block launch (2.5 blocks/CU) — cross-GEMM TLP covers the
// latency that 1-block/CU couldn't.  All are the <128,128,64,64> shape.
struct GP {
  const unsigned short* A; const unsigned short* B; unsigned short* C;
  int Kd, lda, ldb, ldc, Hb, gx, gy;
  long sAb, sAh, sBb, sBh, sCb, sCh;
};

__global__ __launch_bounds__(256) void gemm_merged(GP g0, GP g1, GP g2,
                                                   int n0b, int n1b)
{
  GP p; int rid;
  {
    int id = blockIdx.x;
    if (id < n0b){ p = g0; rid = id; }
    else if (id < n0b + n1b){ p = g1; rid = id - n0b; }
    else { p = g2; rid = id - n0b - n1b; }
  }
  int bx = rid % p.gx; rid /= p.gx;
  int by = rid % p.gy; int z = rid / p.gy;
  const int bb = z / p.Hb, hh = z - bb*p.Hb;

  const unsigned short* Ap = p.A + bb*p.sAb + hh*p.sAh;
  const unsigned short* Bp = p.B + bb*p.sBb + hh*p.sBh;
  unsigned short* Cp = p.C + bb*p.sCb + hh*p.sCh;
  const int m0 = bx*128, n0 = by*128;
  const int t = threadIdx.x, w = t>>6, l = t&63;
  const int wm0 = (w & 1)*64, wn0 = (w >> 1)*64;
  const int lq = l>>4, lm = l&15;

  __shared__ __align__(16) unsigned short As[4][4*128*8];   // 32 KB
  __shared__ __align__(16) unsigned short Bs[4][4*128*8];   // 32 KB

  f32x4 acc[4][4];
  #pragma unroll
  for (int mf=0; mf<4; ++mf)
    #pragma unroll
    for (int nf=0; nf<4; ++nf)
      acc[mf][nf] = f32x4{0.f,0.f,0.f,0.f};

  auto stage = [&](int buf, int k0){
    #pragma unroll
    for (int o = 0; o < 2; ++o){
      int g = o*256 + t;
      int row = g & 127, kq = g >> 7;
      gl_lds16(Ap + (long)(m0+row)*p.lda + k0 + kq*8, &As[buf][(o*256 + w*64)*8]);
    }
    #pragma unroll
    for (int o = 0; o < 2; ++o){
      int g = o*256 + t;
      int row = g & 127, kq = g >> 7;
      gl_lds16(Bp + (long)(n0+row)*p.ldb + k0 + kq*8, &Bs[buf][(o*256 + w*64)*8]);
    }
  };

  const int nIter = p.Kd >> 5;
  stage(0, 0);
  if (1 < nIter) stage(1, 32);
  if (2 < nIter) stage(2, 64);

  for (int it = 0; it < nIter; ++it){
    const int cur = it & 3;
    const int rem = nIter - it;
    if (rem >= 3)      wait_vmcnt<8>();
    else if (rem == 2) wait_vmcnt<4>();
    else               wait_vmcnt<0>();
    __builtin_amdgcn_s_barrier();

    short8 af[4], bfr[4];
    #pragma unroll
    for (int mf=0; mf<4; ++mf)
      af[mf] = *(const short8*)&As[cur][(lq*128 + wm0 + mf*16 + lm)*8];
    #pragma unroll
    for (int nf=0; nf<4; ++nf)
      bfr[nf] = *(const short8*)&Bs[cur][(lq*128 + wn0 + nf*16 + lm)*8];
    #pragma unroll
    for (int mf=0; mf<4; ++mf)
      #pragma unroll
      for (int nf=0; nf<4; ++nf)
        acc[mf][nf] = __builtin_amdgcn_mfma_f32_16x16x32_bf16(
            af[mf], bfr[nf], acc[mf][nf], 0, 0, 0);

    if (it+3 < nIter) stage((it+3) & 3, (it+3)*32);
  }

  #pragma unroll
  for (int mf=0; mf<4; ++mf){
    #pragma unroll
    for (int nf=0; nf<4; ++nf){
      int row = m0 + wm0 + mf*16 + lq*4;
      int col = n0 + wn0 + nf*16 + lm;
      #pragma unroll
      for (int r=0; r<4; ++r)
        Cp[(long)(row+r)*p.ldc + col] = f2bs(acc[mf][nf][r]);
    }
  }
}

// ---------------------------------------------------------------------------
// q_fused (r6 best, 57.8 µs): BM=64, 512 blocks (2/CU).  Column-pair wave
// split; A-frags in registers; counted-vmcnt pipeline across 3 barriers.
__global__ __launch_bounds__(256) void q_fused(
    const unsigned short* __restrict__ A,    // q_hk [2048][2048]
    const unsigned short* __restrict__ W1t,  // wkcqT [16][1536][128]
    const unsigned short* __restrict__ W2t,  // WqrT  [16][64][1536]
    const float4* __restrict__ rq,           // [1024][768]
    unsigned short* __restrict__ qrOut)      // q_rb [B,H,1024,64]
{
  const int z = blockIdx.z, bb = z>>4, hh = z&15;
  const int m0 = blockIdx.x*64;
  const unsigned short* Ap = A + (long)bb*2097152 + hh*128;   // row stride 2048
  const unsigned short* W1 = W1t + (long)hh*196608;           // [1536][128]
  const unsigned short* W2 = W2t + (long)hh*98304;            // [64][1536]
  unsigned short* qo = qrOut + ((long)z*1024 + m0)*64;

  const int t = threadIdx.x, w = t>>6, l = t&63;
  const int lq = l>>4, lm = l&15;
  const int wr = (w>>1)*32;      // wave row-block
  const int wc = w&1;            // wave col-half

  __shared__ __align__(16) unsigned short W1s[2][16*64*8];   // 32 KB
  __shared__ __align__(16) unsigned short W2s[2][8*64*8];    // 16 KB
  __shared__ __align__(16) unsigned short Ps[64*72];         // 9 KB

  // A fragments straight from global (one-time, L2-resident): af[mf][ks]
  short8 af[2][4];
  #pragma unroll
  for (int mf=0; mf<2; ++mf)
    #pragma unroll
    for (int ks=0; ks<4; ++ks)
      af[mf][ks] = *(const short8*)&Ap[(long)(m0 + wr + mf*16 + lm)*2048 + (ks*4+lq)*8];

  auto stageW = [&](int buf, int cn){
    // W1 chunk rows: 0..31 -> lo cols cn*32+row ; 32..63 -> hi cols 736+cn*32+row
    #pragma unroll
    for (int o=0;o<4;++o){
      int g=o*256+t; int row=g&63, kq=g>>6;
      int grow = (row<32) ? (cn*32+row) : (736+cn*32+row);
      gl_lds16(W1 + (long)grow*128 + kq*8, &W1s[buf][(o*256+w*64)*8]);
    }
    // W2 chunk: [kq 8][n 64][8]; k<32 lo, k>=32 hi
    #pragma unroll
    for (int o=0;o<2;++o){
      int g=o*256+t; int n=g&63, kq=g>>6;
      int qk = (kq<4) ? (cn*32+kq*8) : (736+cn*32+kq*8);
      gl_lds16(W2 + (long)n*1536 + qk, &W2s[buf][(o*256+w*64)*8]);
    }
  };
  stageW(0, 0);

  f32x4 accr[2][2];
  #pragma unroll
  for (int mf=0; mf<2; ++mf)
    #pragma unroll
    for (int nf=0; nf<2; ++nf) accr[mf][nf] = f32x4{0.f,0.f,0.f,0.f};

  for (int cn = 0; cn < 24; ++cn){
    const int cur = cn & 1;

    // (1) rq prefetch to regs: rows wr+mf*16+lq*4+r, j = cn*32 + wc*16 + lm
    float4 rc_reg[2][4];
    #pragma unroll
    for (int mf=0; mf<2; ++mf)
      #pragma unroll
      for (int r=0; r<4; ++r){
        int srow = m0 + wr + mf*16 + lq*4 + r;
        rc_reg[mf][r] = rq[(long)srow*768 + cn*32 + wc*16 + lm];
      }
    // (2) stage next chunk (6 loads)
    if (cn < 23) stageW(cur^1, cn+1);
    // (3) wait chunk cn resident: newer = 8 rq + 6 stage(next)
    if (cn < 23) wait_vmcnt<14>(); else wait_vmcnt<8>();
    __builtin_amdgcn_s_barrier();

    // S: 32 rows x (16 lo + 16 hi), K=128 — 8 frag reads, 16 MFMA
    f32x4 sa[2][2];   // [mf][lo/hi]
    #pragma unroll
    for (int mf=0; mf<2; ++mf)
      #pragma unroll
      for (int p=0; p<2; ++p) sa[mf][p] = f32x4{0.f,0.f,0.f,0.f};
    #pragma unroll
    for (int ks=0; ks<4; ++ks){
      short8 blo = *(const short8*)&W1s[cur][((ks*4+lq)*64 + wc*16 + lm)*8];
      short8 bhi = *(const short8*)&W1s[cur][((ks*4+lq)*64 + 32 + wc*16 + lm)*8];
      sa[0][0] = __builtin_amdgcn_mfma_f32_16x16x32_bf16(af[0][ks], blo, sa[0][0], 0,0,0);
      sa[0][1] = __builtin_amdgcn_mfma_f32_16x16x32_bf16(af[0][ks], bhi, sa[0][1], 0,0,0);
      sa[1][0] = __builtin_amdgcn_mfma_f32_16x16x32_bf16(af[1][ks], blo, sa[1][0], 0,0,0);
      sa[1][1] = __builtin_amdgcn_mfma_f32_16x16x32_bf16(af[1][ks], bhi, sa[1][1], 0,0,0);
    }

    // RoPE in registers (lo<->hi pair in-thread), write P to LDS
    #pragma unroll
    for (int mf=0; mf<2; ++mf)
      #pragma unroll
      for (int r=0; r<4; ++r){
        int prow = wr + mf*16 + lq*4 + r;
        float4 rc = rc_reg[mf][r];
        float xl = sa[mf][0][r], xh = sa[mf][1][r];
        Ps[prow*72 + wc*16 + lm]      = f2bs(xl*rc.x - xh*rc.y);
        Ps[prow*72 + 32 + wc*16 + lm] = f2bs(xh*rc.z + xl*rc.w);
      }
    asm volatile("s_waitcnt lgkmcnt(0)" ::: "memory");
    __builtin_amdgcn_sched_barrier(0);
    __builtin_amdgcn_s_barrier();   // mid-barrier: all P visible (no vmcnt drain)

    // PV: rows wr..wr+31, out cols wc*32..+31, K=64 — 8 reads, 8 MFMA
    #pragma unroll
    for (int ks=0; ks<2; ++ks){
      short8 ap0 = *(const short8*)&Ps[(wr + lm)*72 + ks*32 + lq*8];
      short8 ap1 = *(const short8*)&Ps[(wr + 16 + lm)*72 + ks*32 + lq*8];
      #pragma unroll
      for (int nf=0; nf<2; ++nf){
        short8 bw = *(const short8*)&W2s[cur][((ks*4+lq)*64 + wc*32 + nf*16 + lm)*8];
        accr[0][nf] = __builtin_amdgcn_mfma_f32_16x16x32_bf16(ap0, bw, accr[0][nf], 0,0,0);
        accr[1][nf] = __builtin_amdgcn_mfma_f32_16x16x32_bf16(ap1, bw, accr[1][nf], 0,0,0);
      }
    }
    __builtin_amdgcn_s_barrier();   // end barrier: buffer/P overwrite guard
  }

  #pragma unroll
  for (int mf=0; mf<2; ++mf)
    #pragma unroll
    for (int nf=0; nf<2; ++nf)
      #pragma unroll
      for (int r=0; r<4; ++r)
        qo[(long)(wr + mf*16 + lq*4 + r)*64 + wc*32 + nf*16 + lm] = f2bs(accr[mf][nf][r]);
}

// ---------------------------------------------------------------------------
// MFMA flash attention, counted-vmcnt 2-barrier K/V staging.
// K layout is now [b][l][h*64+r] (k_r merged GEMM output): kbase row stride 1024.
__global__ __launch_bounds__(256) void flash_mfma(
    const unsigned short* __restrict__ qr, const unsigned short* __restrict__ kr,
    const unsigned short* __restrict__ vt, unsigned short* __restrict__ ctx)
{
  const int b = blockIdx.z, h = blockIdx.y, s0 = blockIdx.x*64;
  const int t = threadIdx.x, w = t>>6, l = t&63;
  const int lq = l>>4, lm = l&15;

  __shared__ __align__(16) unsigned short Qs[8*64*8];
  __shared__ __align__(16) unsigned short Ks[2][8*64*8];
  __shared__ __align__(16) unsigned short Vts[2][8*128*8];
  __shared__ __align__(16) unsigned short Ps[64*72];

  const unsigned short* qbase = qr + ((long)(b*16+h)*1024 + s0)*64;
  const unsigned short* kbase = kr + (long)b*1048576 + h*64;   // [b][l][h*64+r]
  const unsigned short* vbase = vt + (long)(b*16+h)*131072;

  auto stageKV = [&](int buf, int l0){
    #pragma unroll
    for (int o = 0; o < 2; ++o){
      int g = o*256 + t;
      int row = g & 63, kq = g >> 6;
      gl_lds16(kbase + (long)(l0+row)*1024 + kq*8, &Ks[buf][(o*256 + w*64)*8]);
    }
    #pragma unroll
    for (int o = 0; o < 4; ++o){
      int g = o*256 + t;
      int row = g & 127, kq = g >> 7;
      gl_lds16(vbase + (long)row*1024 + l0 + kq*8, &Vts[buf][(o*256 + w*64)*8]);
    }
  };

  #pragma unroll
  for (int o = 0; o < 2; ++o){
    int g = o*256 + t;
    int row = g & 63, kq = g >> 6;
    gl_lds16(qbase + (long)row*64 + kq*8, &Qs[(o*256 + w*64)*8]);
  }
  stageKV(0, 0);
  __syncthreads();
  short8 aq[2];
  #pragma unroll
  for (int ks = 0; ks < 2; ++ks)
    aq[ks] = *(const short8*)&Qs[((ks*4+lq)*64 + w*16 + lm)*8];

  float m_run[4], l_run[4];
  #pragma unroll
  for (int r = 0; r < 4; ++r){ m_run[r] = -3e38f; l_run[r] = 0.f; }
  f32x4 acc_o[8];
  #pragma unroll
  for (int nf = 0; nf < 8; ++nf) acc_o[nf] = f32x4{0.f,0.f,0.f,0.f};

  for (int it = 0; it < 16; ++it){
    const int cur = it & 1;
    if (it < 15){ stageKV(cur^1, (it+1)*64); wait_vmcnt<6>(); }
    else        { wait_vmcnt<0>(); }
    __builtin_amdgcn_s_barrier();

    f32x4 acc_s[4];
    #pragma unroll
    for (int nf = 0; nf < 4; ++nf) acc_s[nf] = f32x4{0.f,0.f,0.f,0.f};
    #pragma unroll
    for (int ks = 0; ks < 2; ++ks)
      #pragma unroll
      for (int nf = 0; nf < 4; ++nf){
        short8 bf = *(const short8*)&Ks[cur][((ks*4+lq)*64 + nf*16 + lm)*8];
        acc_s[nf] = __builtin_amdgcn_mfma_f32_16x16x32_bf16(
            aq[ks], bf, acc_s[nf], 0, 0, 0);
      }

    float tmax[4];
    #pragma unroll
    for (int r = 0; r < 4; ++r)
      tmax[r] = fmaxf(fmaxf(acc_s[0][r], acc_s[1][r]),
                      fmaxf(acc_s[2][r], acc_s[3][r]));
    #pragma unroll
    for (int mask = 1; mask < 16; mask <<= 1)
      #pragma unroll
      for (int r = 0; r < 4; ++r)
        tmax[r] = fmaxf(tmax[r], __shfl_xor(tmax[r], mask));
    float alpha[4], rsum[4];
    #pragma unroll
    for (int r = 0; r < 4; ++r){
      float mnew = fmaxf(m_run[r], tmax[r]);
      alpha[r] = __expf(m_run[r] - mnew);
      m_run[r] = mnew;
      rsum[r] = 0.f;
    }
    #pragma unroll
    for (int nf = 0; nf < 4; ++nf)
      #pragma unroll
      for (int r = 0; r < 4; ++r){
        float p = __expf(acc_s[nf][r] - m_run[r]);
        rsum[r] += p;
        Ps[(w*16 + lq*4 + r)*72 + nf*16 + lm] = f2bs(p);
      }
    #pragma unroll
    for (int mask = 1; mask < 16; mask <<= 1)
      #pragma unroll
      for (int r = 0; r < 4; ++r)
        rsum[r] += __shfl_xor(rsum[r], mask);
    #pragma unroll
    for (int r = 0; r < 4; ++r)
      l_run[r] = l_run[r]*alpha[r] + rsum[r];

    #pragma unroll
    for (int nf = 0; nf < 8; ++nf)
      #pragma unroll
      for (int r = 0; r < 4; ++r)
        acc_o[nf][r] *= alpha[r];

    short8 ap[2];
    #pragma unroll
    for (int ks = 0; ks < 2; ++ks)
      ap[ks] = *(const short8*)&Ps[(w*16 + lm)*72 + ks*32 + lq*8];
    #pragma unroll
    for (int ks = 0; ks < 2; ++ks)
      #pragma unroll
      for (int nf = 0; nf < 8; ++nf){
        short8 bv = *(const short8*)&Vts[cur][((ks*4+lq)*128 + nf*16 + lm)*8];
        acc_o[nf] = __builtin_amdgcn_mfma_f32_16x16x32_bf16(
            ap[ks], bv, acc_o[nf], 0, 0, 0);
      }
    __builtin_amdgcn_s_barrier();   // buffer-overwrite guard (no drain)
  }

  float inv[4];
  #pragma unroll
  for (int r = 0; r < 4; ++r) inv[r] = 1.f / l_run[r];
  #pragma unroll
  for (int nf = 0; nf < 8; ++nf)
    #pragma unroll
    for (int r = 0; r < 4; ++r){
      long row = (long)b*1024 + s0 + w*16 + lq*4 + r;
      ctx[row*2048 + h*128 + nf*16 + lm] = f2bs(acc_o[nf][r]*inv[r]);
    }
}

// ---------------------------------------------------------------------------
extern "C" void kernel_launch(void* const* d_in, const int* in_sizes, int n_in,
                              void* d_out, int out_size, void* d_ws, size_t ws_size,
                              hipStream_t stream)
{
  const float* hidden_q = (const float*)d_in[0];   // [2,1024,2048]
  const float* kv_c     = (const float*)d_in[1];   // [2,1024,512]
  const float* Wq       = (const float*)d_in[2];   // [2048,2048]
  const float* w_kc_q   = (const float*)d_in[3];   // [16,128,1536]
  const float* w_kc_kv  = (const float*)d_in[4];   // [16,128,512]
  const float* W_qr     = (const float*)d_in[5];   // [16,1536,64]
  const float* W_kr     = (const float*)d_in[6];   // [16,512,64]
  const float* Wo       = (const float*)d_in[7];   // [2048,2048]
  float* out = (float*)d_out;

  char* wsb = (char*)d_ws;
  size_t off = 0;
  auto take = [&](size_t bytes)->void*{
    void* p = wsb + off; off += (bytes + 255) & ~(size_t)255; return p;
  };
  unsigned short* q_rb  = (unsigned short*)take(4194304);   // [B,H,S,64] bf16
  unsigned short* k_rb  = (unsigned short*)take(4194304);   // [B,L,H*64] bf16 (new layout)
  unsigned short* kv_rb = (unsigned short*)take(2097152);   // [B,L,512] bf16
  float4* ropeq4 = (float4*)take(12582912);                 // [1024][768] float4
  unsigned short* q_hk   = (unsigned short*)take(8388608);  // [B*S,2048] bf16
  unsigned short* wkcqT  = (unsigned short*)take(6291456);  // [16][1536][128] bf16
  unsigned short* WqrT   = (unsigned short*)take(3145728);  // [16][64][1536] bf16
  unsigned short* wkckvb = (unsigned short*)take(2097152);  // [16][128][512] bf16
  unsigned short* WkrT   = (unsigned short*)take(1048576);  // [16][64][512] bf16
  unsigned short* Vt     = (unsigned short*)take(8388608);  // [B,H,128,1024] bf16
  unsigned short* hiddenb = (unsigned short*)take(8388608); // bf16 hidden
  unsigned short* Wqb     = (unsigned short*)take(8388608); // bf16 Wq
  unsigned short* Wob     = (unsigned short*)take(8388608); // bf16 Wo
  unsigned short* ctx_lat = (unsigned short*)take(8388608); // [B*S,2048] bf16

  // all preprocessing (tables, k-RoPE, converts, transposes) in one launch
  prep_all<<<22528, 256, 0, stream>>>(ropeq4,
      kv_c, kv_rb,
      hidden_q, hiddenb, Wq, Wqb, w_kc_kv, wkckvb, Wo, Wob,
      w_kc_q, wkcqT, W_qr, WqrT, W_kr, WkrT);

  // 2+7+7b) merged: q_hk (256 blk) + k_r-as-one-GEMM (128 blk) + Vt (256 blk)
  //   k_r: per b, kv_rb[b] [1024x512] @ WkrT-flat [1024x512]^T -> [b][l][h*64+r]
  GP g0{hiddenb, Wqb, q_hk,   2048, 2048, 2048, 2048, 1, 16, 16, 0, 0, 0, 0, 0, 0};
  GP g1{kv_rb,  WkrT, k_rb,    512,  512,  512, 1024, 1,  8,  8, 524288, 0, 0, 0, 1048576, 0};
  GP g2{wkckvb, kv_rb, Vt,     512,  512,  512, 1024, 16, 1,  8, 0, 65536, 524288, 0, 2097152, 131072};
  gemm_merged<<<640, 256, 0, stream>>>(g0, g1, g2, 256, 128);

  // 3+4+5) q_r = RoPE(q_hk @ w_kc_q_T) @ W_qr_T, fused — r6 best variant
  q_fused<<<dim3(16,1,32),256,0,stream>>>(q_hk, wkcqT, WqrT, ropeq4, q_rb);

  // 8) MFMA flash attention -> ctx_lat bf16 [b,s][h*128+k]
  flash_mfma<<<dim3(16,16,2),256,0,stream>>>(q_rb, k_rb, Vt, ctx_lat);

  // 10) out = ctx_lat @ Wo^T  (2048x2048x2048) -> fp32
  gemm_mfma<128,128,64,64,float><<<dim3(16,16,1),256,0,stream>>>(
      ctx_lat, Wob, out, 2048, 2048,2048,2048, 1, 0,0, 0,0, 0,0);
}